// Round 4
// baseline (415.815 us; speedup 1.0000x reference)
//
#include <hip/hip_runtime.h>
#include <stdint.h>

#define M_DIM 8192
#define N_DIM 4096
#define K_DIM 4096

typedef int v4i __attribute__((ext_vector_type(4)));

// ---------------------------------------------------------------------------
// async global->LDS copy, 16 B per lane (wave-uniform LDS base + lane*16)
// ---------------------------------------------------------------------------
typedef __attribute__((address_space(1))) const void gas_void;
typedef __attribute__((address_space(3))) void las_void;

__device__ __forceinline__ void async_copy16(const uint8_t* g, uint8_t* l) {
    __builtin_amdgcn_global_load_lds((gas_void*)g, (las_void*)l, 16, 0, 0);
}

__device__ __forceinline__ int quant1(float x, float scale) {
    // Matches jnp.clip(jnp.round(x/scale), -127, 127): IEEE fp32 divide +
    // round-to-nearest-even (v_rndne), then clamp.
    float q = __builtin_rintf(x / scale);
    q = fminf(127.0f, fmaxf(-127.0f, q));
    return (int)q;
}

__device__ __forceinline__ uint32_t pack4(int q0, int q1, int q2, int q3) {
    return (uint32_t)(q0 & 255) | ((uint32_t)(q1 & 255) << 8) |
           ((uint32_t)(q2 & 255) << 16) | ((uint32_t)(q3 & 255) << 24);
}

// ---------------------------------------------------------------------------
// Kernel 1: per-row absmax + quantize lhs -> qlhs [M][K] int8 row-major
// ---------------------------------------------------------------------------
__global__ __launch_bounds__(256) void quant_lhs_kernel(
    const float* __restrict__ lhs, uint8_t* __restrict__ qlhs,
    float* __restrict__ lhs_scale) {
    const int row = blockIdx.x;
    const int tid = threadIdx.x;
    const float4* src = (const float4*)(lhs + (size_t)row * K_DIM);

    float4 v[4];
    float m = 0.0f;
#pragma unroll
    for (int i = 0; i < 4; ++i) {
        v[i] = src[tid + i * 256];
        m = fmaxf(m, fmaxf(fmaxf(fabsf(v[i].x), fabsf(v[i].y)),
                           fmaxf(fabsf(v[i].z), fabsf(v[i].w))));
    }
#pragma unroll
    for (int off = 32; off > 0; off >>= 1)
        m = fmaxf(m, __shfl_down(m, off, 64));

    __shared__ float wmax[4];
    if ((tid & 63) == 0) wmax[tid >> 6] = m;
    __syncthreads();
    const float mm = fmaxf(fmaxf(wmax[0], wmax[1]), fmaxf(wmax[2], wmax[3]));
    const float scale = (mm == 0.0f) ? 1.0f : mm / 127.0f;
    if (tid == 0) lhs_scale[row] = scale;

    uint32_t* dst = (uint32_t*)(qlhs + (size_t)row * K_DIM);
#pragma unroll
    for (int i = 0; i < 4; ++i) {
        dst[tid + i * 256] = pack4(quant1(v[i].x, scale), quant1(v[i].y, scale),
                                   quant1(v[i].z, scale), quant1(v[i].w, scale));
    }
}

// ---------------------------------------------------------------------------
// Kernel 2a: rhs column absmax, float4-vectorized (4 cols/thread, 32 rows).
// atomicMax on float bits (monotone for non-negative floats).
// Grid: (N/1024, 128).
// ---------------------------------------------------------------------------
__global__ __launch_bounds__(256) void rhs_max_kernel(
    const float* __restrict__ rhs, uint32_t* __restrict__ maxbits) {
    const int c4 = (blockIdx.x * 256 + threadIdx.x) * 4;
    const int r0 = blockIdx.y * 32;
    float m0 = 0.0f, m1 = 0.0f, m2 = 0.0f, m3 = 0.0f;
#pragma unroll
    for (int r = 0; r < 32; ++r) {
        const float4 v = *(const float4*)(rhs + (size_t)(r0 + r) * N_DIM + c4);
        m0 = fmaxf(m0, fabsf(v.x));
        m1 = fmaxf(m1, fabsf(v.y));
        m2 = fmaxf(m2, fabsf(v.z));
        m3 = fmaxf(m3, fabsf(v.w));
    }
    atomicMax(&maxbits[c4 + 0], __float_as_uint(m0));
    atomicMax(&maxbits[c4 + 1], __float_as_uint(m1));
    atomicMax(&maxbits[c4 + 2], __float_as_uint(m2));
    atomicMax(&maxbits[c4 + 3], __float_as_uint(m3));
}

// ---------------------------------------------------------------------------
// Kernel 2b: quantize + transpose rhs -> qrhsT [N][K] int8 row-major.
// Scale computed inline from maxbits (same m/127.0f op as reference).
// Grid: (N/64, K/128) = (64, 32).
// ---------------------------------------------------------------------------
__global__ __launch_bounds__(256) void quant_rhs_t_kernel(
    const float* __restrict__ rhs, const uint32_t* __restrict__ maxbits,
    uint8_t* __restrict__ qrhsT) {
    __shared__ __align__(16) uint8_t tile[64 * 132];  // [n][k + 4B pad]
    const int nbase = blockIdx.x * 64;
    const int kbase = blockIdx.y * 128;
    const int tid = threadIdx.x;

    const int n0 = (tid & 15) * 4;
    float s[4];
#pragma unroll
    for (int j = 0; j < 4; ++j) {
        const float m = __uint_as_float(maxbits[nbase + n0 + j]);
        s[j] = (m == 0.0f) ? 1.0f : m / 127.0f;
    }

#pragma unroll
    for (int p = 0; p < 2; ++p) {
        const int k0 = (tid >> 4) * 4 + p * 64;
        int q[4][4];  // [i = k offset][j = n offset]
#pragma unroll
        for (int i = 0; i < 4; ++i) {
            const float4 v = *(const float4*)(
                rhs + (size_t)(kbase + k0 + i) * N_DIM + nbase + n0);
            q[i][0] = quant1(v.x, s[0]);
            q[i][1] = quant1(v.y, s[1]);
            q[i][2] = quant1(v.z, s[2]);
            q[i][3] = quant1(v.w, s[3]);
        }
#pragma unroll
        for (int j = 0; j < 4; ++j) {
            *(uint32_t*)(tile + (n0 + j) * 132 + k0) =
                pack4(q[0][j], q[1][j], q[2][j], q[3][j]);
        }
    }
    __syncthreads();

#pragma unroll
    for (int p = 0; p < 2; ++p) {
        const int c = tid + p * 256;
        const int n = c >> 3;
        const int g = c & 7;
        uint32_t d[4];
#pragma unroll
        for (int w = 0; w < 4; ++w)
            d[w] = *(const uint32_t*)(tile + n * 132 + g * 16 + w * 4);
        uint4 u;
        u.x = d[0]; u.y = d[1]; u.z = d[2]; u.w = d[3];
        *(uint4*)(qrhsT + (size_t)(nbase + n) * K_DIM + kbase + g * 16) = u;
    }
}

// ---------------------------------------------------------------------------
// Kernel 3: int8 GEMM, 256(M)x128(N) tile, 8 waves (4Mx2N, 64x64 per wave).
//
// R4 design: TLP-driven overlap. 3-slot LDS ring of 24 KB (A 16K + B 8K) =
// 72 KB/block -> TWO blocks resident per CU (144 KB of 160); 16 waves/CU,
// 4 waves/SIMD (VGPR capped at 128 via __launch_bounds__(512,4); acc is only
// 64 regs/wave at 64x64 output). The two blocks are unsynchronized, so when
// one block's waves stall on lgkm/barrier the other block feeds the MFMA
// pipe -- the cross-wave overlap that R2/R3's single-block schedule could
// never achieve (measured: MFMA+LDS ran serially, 2529 cyc/tile).
//
// Pipeline per K-tile t: compute from slot t%3; stage tile t+2 into slot
// (t+2)%3 (3 DMAs/thread: A-lo, A-hi, B); end with s_waitcnt vmcnt(3)
// (stage(t+1) landed, stage(t+2)'s 3 loads stay in flight -- never drained
// to 0 in-loop) + s_barrier. 8 ds_read_b128/wave/tile with a counted lgkm
// ladder: lgkm(3/2/1/0) before each 4-MFMA row.
//
// LDS slot: A [256 rows][64 B] at 0, B [128 rows][64 B] at 16384. 16B chunk
// g of row r stored at chunk g ^ ((r>>1)&3) (zero-conflict swizzle,
// measured); applied on the global source address for staging
// (global_load_lds writes linearly) and on the ds_read address.
//
// Grid 32x32 tiles, XCD-swizzled: 8 XCDs x 16x8 tile regions (bijective).
// ---------------------------------------------------------------------------
__global__ __launch_bounds__(512, 4) void gemm_i8_kernel(
    const uint8_t* __restrict__ qlhs, const uint8_t* __restrict__ qrhsT,
    const float* __restrict__ lhs_scale, const uint32_t* __restrict__ maxbits,
    float* __restrict__ out) {
    extern __shared__ __align__(16) uint8_t smem[];  // 3 * 24576

    const int tid = threadIdx.x;
    const int wave = tid >> 6;
    const int lane = tid & 63;

    // ---- XCD-aware tile swizzle: 1024 blocks -> 8 XCD regions of 16x8 tiles
    const int obid = blockIdx.y * 32 + blockIdx.x;  // grid (32, 32)
    const int xcd = obid & 7;
    const int local = obid >> 3;                     // 0..127
    const int ty = (xcd >> 2) * 16 + (local >> 3);   // 0..31 (M-tiles)
    const int tx = (xcd & 3) * 8 + (local & 7);      // 0..31 (N-tiles)
    const int bm = ty * 256;
    const int bn = tx * 128;

    // ---- staging map: thread t covers 16B chunk (row = t>>2, chunk = t&3)
    // of a 128-row x 64B half; source chunk pre-swizzled so LDS is linear.
    const int srow = tid >> 2;
    const int gsrc = (((tid & 3) ^ ((tid >> 3) & 3)) << 4);
    const uint8_t* gA = qlhs + (size_t)(bm + srow) * K_DIM + gsrc;   // A rows 0-127
    const uint8_t* gA2 = gA + (size_t)128 * K_DIM;                   // A rows 128-255
    const uint8_t* gB = qrhsT + (size_t)(bn + srow) * K_DIM + gsrc;  // B rows 0-127
    const uint32_t stO = (uint32_t)tid * 16u;

    // ---- fragment read map: row = w? + frag*16 + (lane&15), chunk = lane>>4,
    // swizzled chunk = (lane>>4) ^ ((lane>>1)&3).
    const int wm = (wave >> 1) * 64;  // 4 M-rows of waves
    const int wn = (wave & 1) * 64;   // 2 N-cols of waves
    const uint32_t fg = (uint32_t)((((lane >> 4) ^ ((lane >> 1) & 3)) << 4));
    const uint32_t aoff = (uint32_t)((wm + (lane & 15)) * 64) + fg;
    const uint32_t boff = 16384u + (uint32_t)((wn + (lane & 15)) * 64) + fg;

    v4i acc[4][4] = {};

#define FENCE() asm volatile("" ::: "memory")
#define LGKM(n)                                                 \
    do {                                                        \
        asm volatile("s_waitcnt lgkmcnt(" #n ")" ::: "memory"); \
        __builtin_amdgcn_sched_barrier(0);                      \
    } while (0)
#define MFMA4(mi, av)                                                          \
    do {                                                                       \
        acc[mi][0] = __builtin_amdgcn_mfma_i32_16x16x64_i8(av, vb0,            \
                                                           acc[mi][0], 0, 0, 0); \
        acc[mi][1] = __builtin_amdgcn_mfma_i32_16x16x64_i8(av, vb1,            \
                                                           acc[mi][1], 0, 0, 0); \
        acc[mi][2] = __builtin_amdgcn_mfma_i32_16x16x64_i8(av, vb2,            \
                                                           acc[mi][2], 0, 0, 0); \
        acc[mi][3] = __builtin_amdgcn_mfma_i32_16x16x64_i8(av, vb3,            \
                                                           acc[mi][3], 0, 0, 0); \
    } while (0)

    // Cs = compute slot base, Ss = stage slot base, t = runtime tile index.
#define TILE(Cs, Ss, t, DO_STAGE)                                       \
    do {                                                                \
        v4i vb0, vb1, vb2, vb3, va0, va1, va2, va3;                     \
        /* reads first (critical path; DMAs have 2-tile slack) */       \
        vb0 = *(const v4i*)((Cs) + boff + 0);                           \
        vb1 = *(const v4i*)((Cs) + boff + 1024);                        \
        vb2 = *(const v4i*)((Cs) + boff + 2048);                        \
        vb3 = *(const v4i*)((Cs) + boff + 3072);                        \
        FENCE();                                                        \
        va0 = *(const v4i*)((Cs) + aoff + 0);                           \
        FENCE();                                                        \
        va1 = *(const v4i*)((Cs) + aoff + 1024);                        \
        FENCE();                                                        \
        va2 = *(const v4i*)((Cs) + aoff + 2048);                        \
        FENCE();                                                        \
        va3 = *(const v4i*)((Cs) + aoff + 3072);                        \
        FENCE();                                                        \
        if (DO_STAGE) {                                                 \
            async_copy16(gA, (Ss) + stO);                               \
            async_copy16(gA2, (Ss) + 8192 + stO);                       \
            async_copy16(gB, (Ss) + 16384 + stO);                       \
            if ((t) < 62) {                                             \
                gA += 64; gA2 += 64; gB += 64;                          \
            }                                                           \
        }                                                               \
        FENCE();                                                        \
        __builtin_amdgcn_s_setprio(1);                                  \
        LGKM(3); MFMA4(0, va0);                                         \
        LGKM(2); MFMA4(1, va1);                                         \
        LGKM(1); MFMA4(2, va2);                                         \
        LGKM(0); MFMA4(3, va3);                                         \
        __builtin_amdgcn_s_setprio(0);                                  \
        if (DO_STAGE) {                                                 \
            asm volatile("s_waitcnt vmcnt(3)" ::: "memory");            \
            __builtin_amdgcn_s_barrier();                               \
        }                                                               \
    } while (0)

    uint8_t* const s0 = smem;
    uint8_t* const s1 = smem + 24576;
    uint8_t* const s2 = smem + 49152;

    // ---- prologue: stage tiles 0,1 into slots 0,1 (3 DMAs each)
    async_copy16(gA, s0 + stO);
    async_copy16(gA2, s0 + 8192 + stO);
    async_copy16(gB, s0 + 16384 + stO);
    gA += 64; gA2 += 64; gB += 64;
    async_copy16(gA, s1 + stO);
    async_copy16(gA2, s1 + 8192 + stO);
    async_copy16(gB, s1 + 16384 + stO);
    gA += 64; gA2 += 64; gB += 64;
    asm volatile("s_waitcnt vmcnt(3)" ::: "memory");  // tile 0 landed
    __builtin_amdgcn_s_barrier();

    // ---- main loop: 63 tiles (21 x unroll-3), then tile 63 compute-only
#pragma unroll 1
    for (int tt = 0; tt < 63; tt += 3) {
        TILE(s0, s2, tt + 0, 1);
        TILE(s1, s0, tt + 1, 1);
        TILE(s2, s1, tt + 2, 1);
    }
    TILE(s0, s1, 63, 0);  // 63 % 3 == 0; stage args unused

    // drain dummy DMA before epilogue
    asm volatile("s_waitcnt vmcnt(0)" ::: "memory");

    // ---- epilogue: C/D layout col=lane&15, row=(lane>>4)*4+reg
    const int r0 = bm + wm + (lane >> 4) * 4;
    const int c0 = bn + wn + (lane & 15);
    float rsv[4];
#pragma unroll
    for (int ni = 0; ni < 4; ++ni) {
        const float m = __uint_as_float(maxbits[c0 + ni * 16]);
        rsv[ni] = (m == 0.0f) ? 1.0f : m / 127.0f;
    }
#pragma unroll
    for (int mi = 0; mi < 4; ++mi) {
        float ls[4];
#pragma unroll
        for (int r = 0; r < 4; ++r) ls[r] = lhs_scale[r0 + mi * 16 + r];
#pragma unroll
        for (int ni = 0; ni < 4; ++ni) {
            float* o = out + (size_t)(r0 + mi * 16) * N_DIM + c0 + ni * 16;
#pragma unroll
            for (int r = 0; r < 4; ++r)
                o[(size_t)r * N_DIM] = (float)acc[mi][ni][r] * ls[r] * rsv[ni];
        }
    }
#undef FENCE
#undef LGKM
#undef MFMA4
#undef TILE
}

// ---------------------------------------------------------------------------
// Workspace layout (bytes):
//   qlhs   [0, 33554432)
//   qrhsT  [33554432, 50331648)
//   lhs_scale (float[8192])   @ 50331648
//   maxbits   (uint32[4096])  @ 50380800
// ---------------------------------------------------------------------------
extern "C" void kernel_launch(void* const* d_in, const int* in_sizes, int n_in,
                              void* d_out, int out_size, void* d_ws,
                              size_t ws_size, hipStream_t stream) {
    const float* lhs = (const float*)d_in[0];
    const float* rhs = (const float*)d_in[1];
    float* out = (float*)d_out;

    uint8_t* ws = (uint8_t*)d_ws;
    uint8_t* qlhs = ws;
    uint8_t* qrhsT = ws + 33554432u;
    float* lhs_scale = (float*)(ws + 50331648u);
    uint32_t* maxbits = (uint32_t*)(ws + 50380800u);

    static bool attr_set = false;
    if (!attr_set) {
        hipFuncSetAttribute((const void*)gemm_i8_kernel,
                            hipFuncAttributeMaxDynamicSharedMemorySize,
                            73728);
        attr_set = true;
    }

    hipMemsetAsync(maxbits, 0, N_DIM * sizeof(uint32_t), stream);

    quant_lhs_kernel<<<M_DIM, 256, 0, stream>>>(lhs, qlhs, lhs_scale);
    rhs_max_kernel<<<dim3(N_DIM / 1024, 128), 256, 0, stream>>>(rhs, maxbits);
    quant_rhs_t_kernel<<<dim3(N_DIM / 64, K_DIM / 128), 256, 0, stream>>>(
        rhs, maxbits, qrhsT);
    gemm_i8_kernel<<<dim3(32, 32), 512, 73728, stream>>>(
        qlhs, qrhsT, lhs_scale, maxbits, out);
}